// Round 1
// baseline (975.981 us; speedup 1.0000x reference)
//
#include <hip/hip_runtime.h>
#include <math.h>

#define B_ 4
#define S_ 2048
#define D_ 512
#define H_ 8
#define NEG_FILL (-1e-9f)

typedef __attribute__((ext_vector_type(8))) short bf16x8;
typedef __attribute__((ext_vector_type(4))) float f32x4;

#define MFMA16(A, Bm, C) __builtin_amdgcn_mfma_f32_16x16x32_bf16((A), (Bm), (C), 0, 0, 0)

__device__ __forceinline__ short f2b(float f) {
  union { float f; unsigned u; } x;
  x.f = f;
  unsigned r = x.u + 0x7fffu + ((x.u >> 16) & 1u);
  return (short)(r >> 16);
}

// ---------------------------------------------------------------------------
// prep: W[512x512] fp32 (k-major) -> Wt[n][k] bf16 (transposed), z picks matrix
// ---------------------------------------------------------------------------
__global__ __launch_bounds__(256) void prep_wt(
    const float* __restrict__ Wq, const float* __restrict__ Wk,
    const float* __restrict__ Wv, const float* __restrict__ Wo,
    short* __restrict__ Wqt, short* __restrict__ Wkt,
    short* __restrict__ Wvt, short* __restrict__ Wot)
{
  const float* W; short* Wt;
  switch (blockIdx.z) {
    case 0: W = Wq; Wt = Wqt; break;
    case 1: W = Wk; Wt = Wkt; break;
    case 2: W = Wv; Wt = Wvt; break;
    default: W = Wo; Wt = Wot; break;
  }
  __shared__ float Ws[64 * 68];
  const int t = threadIdx.x;
  const int n0 = blockIdx.x * 64, k0 = blockIdx.y * 64;

  #pragma unroll
  for (int rep = 0; rep < 4; ++rep) {
    int e4 = rep * 256 + t;           // float4 units
    int r = e4 >> 4, c0 = (e4 & 15) * 4;
    *(float4*)&Ws[r * 68 + c0] = *(const float4*)&W[(size_t)(k0 + r) * 512 + n0 + c0];
  }
  __syncthreads();

  int rn = t >> 2;                    // out row (n)
  int kb = (t & 3) * 16;              // out col base (k)
  union { short s[8]; int4 v; } pk;
  #pragma unroll
  for (int half = 0; half < 2; ++half) {
    #pragma unroll
    for (int i = 0; i < 8; ++i)
      pk.s[i] = f2b(Ws[(kb + half * 8 + i) * 68 + rn]);
    *(int4*)&Wt[(size_t)(n0 + rn) * 512 + k0 + kb + half * 8] = pk.v;
  }
}

// ---------------------------------------------------------------------------
// QKV projection, MFMA bf16. X[8192x512] fp32, Wt[n][k] bf16.
// z=0 -> qh[bh][s][64], z=1 -> kh[bh][s][64], z=2 -> vt[bh][d][2048]
// ---------------------------------------------------------------------------
__global__ __launch_bounds__(256) void qkv_mfma(
    const float* __restrict__ q, const float* __restrict__ k, const float* __restrict__ v,
    const short* __restrict__ Wqt, const short* __restrict__ Wkt, const short* __restrict__ Wvt,
    short* __restrict__ qh, short* __restrict__ kh, short* __restrict__ vt)
{
  const int z = blockIdx.z;
  const float* X = (z == 0) ? q : (z == 1) ? k : v;
  const short* Wt = (z == 0) ? Wqt : (z == 1) ? Wkt : Wvt;

  __shared__ short Xs[64 * 72];
  __shared__ short Wsh[64 * 72];

  const int t = threadIdx.x;
  const int wave = t >> 6, lane = t & 63, quad = lane >> 4, l15 = lane & 15;
  const int tile_n = blockIdx.x * 64;
  const int tile_m = blockIdx.y * 64;

  f32x4 acc[4];
  #pragma unroll
  for (int nt = 0; nt < 4; ++nt) acc[nt] = (f32x4){0.f, 0.f, 0.f, 0.f};

  for (int k0 = 0; k0 < 512; k0 += 64) {
    __syncthreads();
    #pragma unroll
    for (int rep = 0; rep < 4; ++rep) {
      int e4 = rep * 256 + t;
      int row = e4 >> 4, c0 = (e4 & 15) * 4;
      float4 xv = *(const float4*)&X[(size_t)(tile_m + row) * 512 + k0 + c0];
      *(short4*)&Xs[row * 72 + c0] =
          make_short4(f2b(xv.x), f2b(xv.y), f2b(xv.z), f2b(xv.w));
    }
    #pragma unroll
    for (int rep = 0; rep < 2; ++rep) {
      int e = rep * 256 + t;
      int row = e >> 3, c0 = (e & 7) * 8;
      *(int4*)&Wsh[row * 72 + c0] = *(const int4*)&Wt[(size_t)(tile_n + row) * 512 + k0 + c0];
    }
    __syncthreads();
    #pragma unroll
    for (int ks = 0; ks < 2; ++ks) {
      bf16x8 af = *(bf16x8*)&Xs[(wave * 16 + l15) * 72 + ks * 32 + quad * 8];
      #pragma unroll
      for (int nt = 0; nt < 4; ++nt) {
        bf16x8 bfr = *(bf16x8*)&Wsh[(nt * 16 + l15) * 72 + ks * 32 + quad * 8];
        acc[nt] = MFMA16(af, bfr, acc[nt]);
      }
    }
  }

  const int h = tile_n >> 6;
  if (z < 2) {
    short* Y = (z == 0) ? qh : kh;
    #pragma unroll
    for (int nt = 0; nt < 4; ++nt) {
      int d = nt * 16 + l15;
      #pragma unroll
      for (int r = 0; r < 4; ++r) {
        int row = tile_m + wave * 16 + quad * 4 + r;
        int b = row >> 11, s = row & (S_ - 1);
        Y[(((size_t)(b * H_ + h)) * S_ + s) * 64 + d] = f2b(acc[nt][r]);
      }
    }
  } else {
    int row0 = tile_m + wave * 16 + quad * 4;
    int b = row0 >> 11, s0 = row0 & (S_ - 1);
    #pragma unroll
    for (int nt = 0; nt < 4; ++nt) {
      int d = nt * 16 + l15;
      short4 pk = make_short4(f2b(acc[nt][0]), f2b(acc[nt][1]),
                              f2b(acc[nt][2]), f2b(acc[nt][3]));
      *(short4*)&vt[(((size_t)(b * H_ + h)) * 64 + d) * S_ + s0] = pk;
    }
  }
}

// ---------------------------------------------------------------------------
// Fused attention, MFMA bf16, BARRIER-FREE main loops.
// Block = (64 q-rows, one bh), 4 waves, each wave owns 16 q-rows.
// Q/K/V fragments are loaded DIRECTLY from global (16B/lane, L1/L2-served) --
// no LDS staging, no __syncthreads in the k-loops. The P->PV transpose goes
// through a per-wave LDS tile (wave-local: only lgkmcnt, no barrier).
// XCD-bijective block swizzle keeps each XCD's working set to 4 bh slices
// (~2 MB K+V) inside its private 4 MiB L2.
// qh/kh: [bh][s][64] bf16 ; vt: [bh][d][2048] bf16.
// Writes attn fp32 [bh][s][2048] and ohb bf16 [b*s][512].
// ---------------------------------------------------------------------------
__global__ __launch_bounds__(256) void attn_mfma(
    const short* __restrict__ qh, const short* __restrict__ kh,
    const short* __restrict__ vt, const int* __restrict__ src_mask,
    float* __restrict__ attn_out, short* __restrict__ ohb)
{
  const int t = threadIdx.x;
  const int wave = t >> 6, lane = t & 63, quad = lane >> 4, l15 = lane & 15;

  // 1024 blocks, 8 XCDs -> contiguous chunk of 128 blocks per XCD.
  const int lin = blockIdx.y * 32 + blockIdx.x;
  const int nl  = (lin & 7) * 128 + (lin >> 3);
  const int bh = nl >> 5, b = bh >> 3, h = bh & 7;
  const int q0 = (nl & 31) * 64;

  __shared__ short Ps[4][16 * 72];   // per-wave P tile [16 rows][64+pad]
  __shared__ int smAll[S_];          // full mask row for this b (8 KB)

  #pragma unroll
  for (int rep = 0; rep < 2; ++rep) {
    int idx = (rep * 256 + t) * 4;
    *(int4*)&smAll[idx] = *(const int4*)&src_mask[b * S_ + idx];
  }
  __syncthreads();                   // the only barrier in this kernel

  const short* __restrict__ khb = kh + (size_t)bh * S_ * 64;
  const short* __restrict__ vtb = vt + (size_t)bh * 64 * S_;

  // Q fragments straight from global (row = wave*16+l15).
  const size_t qrow = (size_t)bh * S_ + q0 + wave * 16 + l15;
  const bf16x8 qf0 = *(const bf16x8*)&qh[qrow * 64 + quad * 8];
  const bf16x8 qf1 = *(const bf16x8*)&qh[qrow * 64 + 32 + quad * 8];

  int rloc[4], mqr[4], qir[4];
  #pragma unroll
  for (int r = 0; r < 4; ++r) {
    rloc[r] = wave * 16 + quad * 4 + r;
    qir[r] = q0 + rloc[r];
    mqr[r] = smAll[qir[r]];
  }

  // ---------------- Pass A: exp-sums (no max subtraction needed) ----------
  float rs[4] = {0.f, 0.f, 0.f, 0.f};
  for (int kt0 = 0; kt0 < S_; kt0 += 64) {
    #pragma unroll
    for (int nt = 0; nt < 4; ++nt) {
      const short* kp = khb + (size_t)(kt0 + nt * 16 + l15) * 64 + quad * 8;
      bf16x8 kf0 = *(const bf16x8*)kp;
      bf16x8 kf1 = *(const bf16x8*)(kp + 32);
      f32x4 c = (f32x4){0.f, 0.f, 0.f, 0.f};
      c = MFMA16(qf0, kf0, c);
      c = MFMA16(qf1, kf1, c);
      int kj = kt0 + nt * 16 + l15;
      int mk = smAll[kj];
      #pragma unroll
      for (int r = 0; r < 4; ++r) {
        float ss = c[r] * 0.125f;
        bool keep = (mqr[r] & mk) || (qir[r] == kj);
        ss = keep ? ss : NEG_FILL;
        rs[r] += __expf(ss);
      }
    }
  }
  // reduce across the 16 lanes holding one row's columns; keep inverse
  #pragma unroll
  for (int r = 0; r < 4; ++r) {
    float vsum = rs[r];
    vsum += __shfl_xor(vsum, 1);
    vsum += __shfl_xor(vsum, 2);
    vsum += __shfl_xor(vsum, 4);
    vsum += __shfl_xor(vsum, 8);
    rs[r] = 1.f / vsum;
  }

  // ---------------- Pass B: attn write + PV ----------------
  f32x4 oacc[4];
  #pragma unroll
  for (int dt = 0; dt < 4; ++dt) oacc[dt] = (f32x4){0.f, 0.f, 0.f, 0.f};

  short* __restrict__ ps = Ps[wave];
  float* __restrict__ arow[4];
  #pragma unroll
  for (int r = 0; r < 4; ++r)
    arow[r] = attn_out + ((size_t)bh * S_ + q0 + rloc[r]) * S_;

  for (int kt0 = 0; kt0 < S_; kt0 += 64) {
    #pragma unroll
    for (int nt = 0; nt < 4; ++nt) {
      const short* kp = khb + (size_t)(kt0 + nt * 16 + l15) * 64 + quad * 8;
      bf16x8 kf0 = *(const bf16x8*)kp;
      bf16x8 kf1 = *(const bf16x8*)(kp + 32);
      f32x4 c = (f32x4){0.f, 0.f, 0.f, 0.f};
      c = MFMA16(qf0, kf0, c);
      c = MFMA16(qf1, kf1, c);
      int kj = kt0 + nt * 16 + l15;
      int mk = smAll[kj];
      #pragma unroll
      for (int r = 0; r < 4; ++r) {
        float ss = c[r] * 0.125f;
        bool keep = (mqr[r] & mk) || (qir[r] == kj);
        ss = keep ? ss : NEG_FILL;
        float p = __expf(ss) * rs[r];
        arow[r][kj] = p;
        ps[(quad * 4 + r) * 72 + nt * 16 + l15] = f2b(p);
      }
    }
    // wave-local P transpose readback: same wave wrote these rows -> no barrier
    bf16x8 pf0 = *(bf16x8*)&ps[l15 * 72 + quad * 8];
    bf16x8 pf1 = *(bf16x8*)&ps[l15 * 72 + 32 + quad * 8];
    #pragma unroll
    for (int dt = 0; dt < 4; ++dt) {
      const short* vp = vtb + (size_t)(dt * 16 + l15) * S_ + kt0 + quad * 8;
      bf16x8 vf0 = *(const bf16x8*)vp;
      bf16x8 vf1 = *(const bf16x8*)(vp + 32);
      oacc[dt] = MFMA16(pf0, vf0, oacc[dt]);
      oacc[dt] = MFMA16(pf1, vf1, oacc[dt]);
    }
  }

  // ---- write O tile (bf16) ----
  #pragma unroll
  for (int dt = 0; dt < 4; ++dt) {
    int d = h * 64 + dt * 16 + l15;
    #pragma unroll
    for (int r = 0; r < 4; ++r)
      ohb[((size_t)b * S_ + q0 + rloc[r]) * 512 + d] = f2b(oacc[dt][r]);
  }
}

// ---------------------------------------------------------------------------
// out = ohb @ Wo + residual(q), MFMA bf16, fp32 out.
// ---------------------------------------------------------------------------
__global__ __launch_bounds__(256) void out_mfma(
    const short* __restrict__ ohb, const short* __restrict__ Wot,
    const float* __restrict__ resid, float* __restrict__ out)
{
  __shared__ short Xs[64 * 72];
  __shared__ short Wsh[64 * 72];

  const int t = threadIdx.x;
  const int wave = t >> 6, lane = t & 63, quad = lane >> 4, l15 = lane & 15;
  const int tile_n = blockIdx.x * 64;
  const int tile_m = blockIdx.y * 64;

  f32x4 acc[4];
  #pragma unroll
  for (int nt = 0; nt < 4; ++nt) acc[nt] = (f32x4){0.f, 0.f, 0.f, 0.f};

  for (int k0 = 0; k0 < 512; k0 += 64) {
    __syncthreads();
    #pragma unroll
    for (int rep = 0; rep < 2; ++rep) {
      int e = rep * 256 + t;
      int row = e >> 3, c0 = (e & 7) * 8;
      *(int4*)&Xs[row * 72 + c0] = *(const int4*)&ohb[(size_t)(tile_m + row) * 512 + k0 + c0];
      *(int4*)&Wsh[row * 72 + c0] = *(const int4*)&Wot[(size_t)(tile_n + row) * 512 + k0 + c0];
    }
    __syncthreads();
    #pragma unroll
    for (int ks = 0; ks < 2; ++ks) {
      bf16x8 af = *(bf16x8*)&Xs[(wave * 16 + l15) * 72 + ks * 32 + quad * 8];
      #pragma unroll
      for (int nt = 0; nt < 4; ++nt) {
        bf16x8 bfr = *(bf16x8*)&Wsh[(nt * 16 + l15) * 72 + ks * 32 + quad * 8];
        acc[nt] = MFMA16(af, bfr, acc[nt]);
      }
    }
  }

  #pragma unroll
  for (int nt = 0; nt < 4; ++nt) {
    int c = tile_n + nt * 16 + l15;
    #pragma unroll
    for (int r = 0; r < 4; ++r) {
      size_t row = tile_m + wave * 16 + quad * 4 + r;
      out[row * 512 + c] = acc[nt][r] + resid[row * 512 + c];
    }
  }
}

// ---------------------------------------------------------------------------
// LayerNorm over last dim (512), one wave per row, in place.
// ---------------------------------------------------------------------------
__global__ __launch_bounds__(256) void ln_kernel(
    float* __restrict__ io, const float* __restrict__ gamma, const float* __restrict__ beta)
{
  const int wid  = threadIdx.x >> 6;
  const int lane = threadIdx.x & 63;
  const size_t row = (size_t)blockIdx.x * 4 + wid;
  const size_t base = row * 512 + lane * 8;

  float4 x0 = *(const float4*)&io[base];
  float4 x1 = *(const float4*)&io[base + 4];
  float xs[8] = {x0.x, x0.y, x0.z, x0.w, x1.x, x1.y, x1.z, x1.w};

  float s = 0.f, s2 = 0.f;
  #pragma unroll
  for (int i = 0; i < 8; ++i) { s += xs[i]; s2 = fmaf(xs[i], xs[i], s2); }
  #pragma unroll
  for (int m = 1; m < 64; m <<= 1) {
    s  += __shfl_xor(s, m);
    s2 += __shfl_xor(s2, m);
  }
  float mu  = s * (1.f / 512.f);
  float var = s2 * (1.f / 512.f) - mu * mu;
  float rsq = rsqrtf(var + 1e-6f);

  float4 g0 = *(const float4*)&gamma[lane * 8];
  float4 g1 = *(const float4*)&gamma[lane * 8 + 4];
  float4 b0 = *(const float4*)&beta[lane * 8];
  float4 b1 = *(const float4*)&beta[lane * 8 + 4];
  float gs[8] = {g0.x, g0.y, g0.z, g0.w, g1.x, g1.y, g1.z, g1.w};
  float bs[8] = {b0.x, b0.y, b0.z, b0.w, b1.x, b1.y, b1.z, b1.w};

  float ys[8];
  #pragma unroll
  for (int i = 0; i < 8; ++i) ys[i] = (xs[i] - mu) * rsq * gs[i] + bs[i];
  *(float4*)&io[base]     = make_float4(ys[0], ys[1], ys[2], ys[3]);
  *(float4*)&io[base + 4] = make_float4(ys[4], ys[5], ys[6], ys[7]);
}

// ---------------------------------------------------------------------------
extern "C" void kernel_launch(void* const* d_in, const int* in_sizes, int n_in,
                              void* d_out, int out_size, void* d_ws, size_t ws_size,
                              hipStream_t stream)
{
  const float* q     = (const float*)d_in[0];
  const float* k     = (const float*)d_in[1];
  const float* v     = (const float*)d_in[2];
  const int*  smask  = (const int*)d_in[3];
  const float* Wq    = (const float*)d_in[4];
  const float* Wk    = (const float*)d_in[5];
  const float* Wv    = (const float*)d_in[6];
  const float* Wo    = (const float*)d_in[7];
  const float* gamma = (const float*)d_in[8];
  const float* beta  = (const float*)d_in[9];

  float* out  = (float*)d_out;
  float* attn = out + (size_t)B_ * S_ * D_;

  short* wsS = (short*)d_ws;
  short* qh  = wsS;                    // [32 bh][2048][64]
  short* kh  = qh + 4194304;
  short* vt  = kh + 4194304;           // [32 bh][64][2048]
  short* ohb = vt + 4194304;           // [8192][512]
  short* Wqt = ohb + 4194304;          // [512][512] each
  short* Wkt = Wqt + 262144;
  short* Wvt = Wkt + 262144;
  short* Wot = Wvt + 262144;

  prep_wt<<<dim3(8, 8, 4), 256, 0, stream>>>(Wq, Wk, Wv, Wo, Wqt, Wkt, Wvt, Wot);
  qkv_mfma<<<dim3(8, 128, 3), 256, 0, stream>>>(q, k, v, Wqt, Wkt, Wvt, qh, kh, vt);
  attn_mfma<<<dim3(32, 32), 256, 0, stream>>>(qh, kh, vt, smask, attn, ohb);
  out_mfma<<<dim3(8, 128), 256, 0, stream>>>(ohb, Wot, q, out);
  ln_kernel<<<2048, 256, 0, stream>>>(out, gamma, beta);
}

// Round 2
// 947.105 us; speedup vs baseline: 1.0305x; 1.0305x over previous
//
#include <hip/hip_runtime.h>
#include <math.h>

#define B_ 4
#define S_ 2048
#define D_ 512
#define H_ 8
#define NEG_FILL (-1e-9f)

typedef __attribute__((ext_vector_type(8))) short bf16x8;
typedef __attribute__((ext_vector_type(4))) float f32x4;

#define MFMA16(A, Bm, C) __builtin_amdgcn_mfma_f32_16x16x32_bf16((A), (Bm), (C), 0, 0, 0)

__device__ __forceinline__ short f2b(float f) {
  union { float f; unsigned u; } x;
  x.f = f;
  unsigned r = x.u + 0x7fffu + ((x.u >> 16) & 1u);
  return (short)(r >> 16);
}

// ---------------------------------------------------------------------------
// prep: W[512x512] fp32 (k-major) -> Wt[n][k] bf16 (transposed), z picks matrix
// ---------------------------------------------------------------------------
__global__ __launch_bounds__(256) void prep_wt(
    const float* __restrict__ Wq, const float* __restrict__ Wk,
    const float* __restrict__ Wv, const float* __restrict__ Wo,
    short* __restrict__ Wqt, short* __restrict__ Wkt,
    short* __restrict__ Wvt, short* __restrict__ Wot)
{
  const float* W; short* Wt;
  switch (blockIdx.z) {
    case 0: W = Wq; Wt = Wqt; break;
    case 1: W = Wk; Wt = Wkt; break;
    case 2: W = Wv; Wt = Wvt; break;
    default: W = Wo; Wt = Wot; break;
  }
  __shared__ float Ws[64 * 68];
  const int t = threadIdx.x;
  const int n0 = blockIdx.x * 64, k0 = blockIdx.y * 64;

  #pragma unroll
  for (int rep = 0; rep < 4; ++rep) {
    int e4 = rep * 256 + t;           // float4 units
    int r = e4 >> 4, c0 = (e4 & 15) * 4;
    *(float4*)&Ws[r * 68 + c0] = *(const float4*)&W[(size_t)(k0 + r) * 512 + n0 + c0];
  }
  __syncthreads();

  int rn = t >> 2;                    // out row (n)
  int kb = (t & 3) * 16;              // out col base (k)
  union { short s[8]; int4 v; } pk;
  #pragma unroll
  for (int half = 0; half < 2; ++half) {
    #pragma unroll
    for (int i = 0; i < 8; ++i)
      pk.s[i] = f2b(Ws[(kb + half * 8 + i) * 68 + rn]);
    *(int4*)&Wt[(size_t)(n0 + rn) * 512 + k0 + kb + half * 8] = pk.v;
  }
}

// ---------------------------------------------------------------------------
// QKV projection, MFMA bf16, async-split staging (T14):
// issue next tile's global loads into regs BEFORE current compute;
// ds_write after the post-compute barrier. Hides HBM/L2 latency.
// ---------------------------------------------------------------------------
__global__ __launch_bounds__(256) void qkv_mfma(
    const float* __restrict__ q, const float* __restrict__ k, const float* __restrict__ v,
    const short* __restrict__ Wqt, const short* __restrict__ Wkt, const short* __restrict__ Wvt,
    short* __restrict__ qh, short* __restrict__ kh, short* __restrict__ vt)
{
  const int z = blockIdx.z;
  const float* X = (z == 0) ? q : (z == 1) ? k : v;
  const short* Wt = (z == 0) ? Wqt : (z == 1) ? Wkt : Wvt;

  __shared__ short Xs[64 * 72];
  __shared__ short Wsh[64 * 72];

  const int t = threadIdx.x;
  const int wave = t >> 6, lane = t & 63, quad = lane >> 4, l15 = lane & 15;
  const int tile_n = blockIdx.x * 64;
  const int tile_m = blockIdx.y * 64;

  // staging coordinates for this thread
  const int xrow = t >> 4, xc = (t & 15) * 4;   // + rep*16 rows (float4 units)
  const int wrow = t >> 3, wc = (t & 7) * 8;    // + rep*32 rows (int4 units)

  f32x4 acc[4];
  #pragma unroll
  for (int nt = 0; nt < 4; ++nt) acc[nt] = (f32x4){0.f, 0.f, 0.f, 0.f};

  float4 xreg[4];
  int4 wreg[2];

  // ---- prologue: stage k0 = 0 ----
  #pragma unroll
  for (int rep = 0; rep < 4; ++rep)
    xreg[rep] = *(const float4*)&X[(size_t)(tile_m + rep * 16 + xrow) * 512 + xc];
  #pragma unroll
  for (int rep = 0; rep < 2; ++rep)
    wreg[rep] = *(const int4*)&Wt[(size_t)(tile_n + rep * 32 + wrow) * 512 + wc];
  #pragma unroll
  for (int rep = 0; rep < 4; ++rep)
    *(short4*)&Xs[(rep * 16 + xrow) * 72 + xc] =
        make_short4(f2b(xreg[rep].x), f2b(xreg[rep].y), f2b(xreg[rep].z), f2b(xreg[rep].w));
  #pragma unroll
  for (int rep = 0; rep < 2; ++rep)
    *(int4*)&Wsh[(rep * 32 + wrow) * 72 + wc] = wreg[rep];
  __syncthreads();

  for (int k0 = 0; k0 < 512; k0 += 64) {
    const bool has_next = (k0 + 64 < 512);
    if (has_next) {
      #pragma unroll
      for (int rep = 0; rep < 4; ++rep)
        xreg[rep] = *(const float4*)&X[(size_t)(tile_m + rep * 16 + xrow) * 512 + k0 + 64 + xc];
      #pragma unroll
      for (int rep = 0; rep < 2; ++rep)
        wreg[rep] = *(const int4*)&Wt[(size_t)(tile_n + rep * 32 + wrow) * 512 + k0 + 64 + wc];
    }
    #pragma unroll
    for (int ks = 0; ks < 2; ++ks) {
      bf16x8 af = *(bf16x8*)&Xs[(wave * 16 + l15) * 72 + ks * 32 + quad * 8];
      #pragma unroll
      for (int nt = 0; nt < 4; ++nt) {
        bf16x8 bfr = *(bf16x8*)&Wsh[(nt * 16 + l15) * 72 + ks * 32 + quad * 8];
        acc[nt] = MFMA16(af, bfr, acc[nt]);
      }
    }
    __syncthreads();
    if (has_next) {
      #pragma unroll
      for (int rep = 0; rep < 4; ++rep)
        *(short4*)&Xs[(rep * 16 + xrow) * 72 + xc] =
            make_short4(f2b(xreg[rep].x), f2b(xreg[rep].y), f2b(xreg[rep].z), f2b(xreg[rep].w));
      #pragma unroll
      for (int rep = 0; rep < 2; ++rep)
        *(int4*)&Wsh[(rep * 32 + wrow) * 72 + wc] = wreg[rep];
    }
    __syncthreads();
  }

  const int h = tile_n >> 6;
  if (z < 2) {
    short* Y = (z == 0) ? qh : kh;
    #pragma unroll
    for (int nt = 0; nt < 4; ++nt) {
      int d = nt * 16 + l15;
      #pragma unroll
      for (int r = 0; r < 4; ++r) {
        int row = tile_m + wave * 16 + quad * 4 + r;
        int b = row >> 11, s = row & (S_ - 1);
        Y[(((size_t)(b * H_ + h)) * S_ + s) * 64 + d] = f2b(acc[nt][r]);
      }
    }
  } else {
    int row0 = tile_m + wave * 16 + quad * 4;
    int b = row0 >> 11, s0 = row0 & (S_ - 1);
    #pragma unroll
    for (int nt = 0; nt < 4; ++nt) {
      int d = nt * 16 + l15;
      short4 pk = make_short4(f2b(acc[nt][0]), f2b(acc[nt][1]),
                              f2b(acc[nt][2]), f2b(acc[nt][3]));
      *(short4*)&vt[(((size_t)(b * H_ + h)) * 64 + d) * S_ + s0] = pk;
    }
  }
}

// ---------------------------------------------------------------------------
// Fused attention, MFMA bf16, LDS-staged K/V with async-split (T14) staging:
// per tile, issue next tile's global loads into regs BEFORE compute;
// ds_write them after the post-compute barrier. Global latency hides under
// the long MFMA+exp compute phase. Mask row cached whole in LDS (8 KB).
// Q fragments direct from global (one-time). P tile wave-local (no barrier).
// XCD-bijective swizzle keeps 4 bh slices (~2 MB K+V) per XCD L2.
// ---------------------------------------------------------------------------
__global__ __launch_bounds__(256) void attn_mfma(
    const short* __restrict__ qh, const short* __restrict__ kh,
    const short* __restrict__ vt, const int* __restrict__ src_mask,
    float* __restrict__ attn_out, short* __restrict__ ohb)
{
  const int t = threadIdx.x;
  const int wave = t >> 6, lane = t & 63, quad = lane >> 4, l15 = lane & 15;

  // 1024 blocks, 8 XCDs -> contiguous chunk of 128 nl per XCD.
  const int lin = blockIdx.y * 32 + blockIdx.x;
  const int nl  = (lin & 7) * 128 + (lin >> 3);
  const int bh = nl >> 5, b = bh >> 3, h = bh & 7;
  const int q0 = (nl & 31) * 64;

  __shared__ short Ks[64 * 72];
  __shared__ short Vs[64 * 72];
  __shared__ short Ps[64 * 72];
  __shared__ int smAll[S_];          // full mask row for this b (8 KB)

  const short* __restrict__ khb = kh + (size_t)bh * S_ * 64;
  const short* __restrict__ vtb = vt + (size_t)bh * 64 * S_;

  // staging coordinates (int4 = 8 shorts)
  const int srow = t >> 3, scol = (t & 7) * 8;   // + rep*32 rows

  // Q fragments straight from global (row = wave*16+l15).
  const size_t qrow = (size_t)bh * S_ + q0 + wave * 16 + l15;
  const bf16x8 qf0 = *(const bf16x8*)&qh[qrow * 64 + quad * 8];
  const bf16x8 qf1 = *(const bf16x8*)&qh[qrow * 64 + 32 + quad * 8];

  // ---- prologue: stage mask row + K tile 0 ----
  int4 mreg[2], kreg[2], vreg[2];
  #pragma unroll
  for (int rep = 0; rep < 2; ++rep)
    mreg[rep] = *(const int4*)&src_mask[b * S_ + (rep * 256 + t) * 4];
  #pragma unroll
  for (int rep = 0; rep < 2; ++rep)
    kreg[rep] = *(const int4*)&khb[(size_t)(rep * 32 + srow) * 64 + scol];
  #pragma unroll
  for (int rep = 0; rep < 2; ++rep) {
    *(int4*)&smAll[(rep * 256 + t) * 4] = mreg[rep];
    *(int4*)&Ks[(rep * 32 + srow) * 72 + scol] = kreg[rep];
  }
  __syncthreads();

  int rloc[4], mqr[4], qir[4];
  #pragma unroll
  for (int r = 0; r < 4; ++r) {
    rloc[r] = wave * 16 + quad * 4 + r;
    qir[r] = q0 + rloc[r];
    mqr[r] = smAll[qir[r]];
  }

  // ---------------- Pass A: exp-sums (no max subtraction needed) ----------
  float rs[4] = {0.f, 0.f, 0.f, 0.f};
  for (int kt0 = 0; kt0 < S_; kt0 += 64) {
    const bool has_next = (kt0 + 64 < S_);
    if (has_next) {
      #pragma unroll
      for (int rep = 0; rep < 2; ++rep)
        kreg[rep] = *(const int4*)&khb[(size_t)(kt0 + 64 + rep * 32 + srow) * 64 + scol];
    }
    #pragma unroll
    for (int nt = 0; nt < 4; ++nt) {
      bf16x8 kf0 = *(bf16x8*)&Ks[(nt * 16 + l15) * 72 + quad * 8];
      bf16x8 kf1 = *(bf16x8*)&Ks[(nt * 16 + l15) * 72 + 32 + quad * 8];
      f32x4 c = (f32x4){0.f, 0.f, 0.f, 0.f};
      c = MFMA16(qf0, kf0, c);
      c = MFMA16(qf1, kf1, c);
      int kj = kt0 + nt * 16 + l15;
      int mk = smAll[kj];
      #pragma unroll
      for (int r = 0; r < 4; ++r) {
        float ss = c[r] * 0.125f;
        bool keep = (mqr[r] & mk) || (qir[r] == kj);
        ss = keep ? ss : NEG_FILL;
        rs[r] += __expf(ss);
      }
    }
    __syncthreads();
    if (has_next) {
      #pragma unroll
      for (int rep = 0; rep < 2; ++rep)
        *(int4*)&Ks[(rep * 32 + srow) * 72 + scol] = kreg[rep];
    }
    __syncthreads();
  }
  // reduce across the 16 lanes holding one row's columns; keep inverse
  #pragma unroll
  for (int r = 0; r < 4; ++r) {
    float vsum = rs[r];
    vsum += __shfl_xor(vsum, 1);
    vsum += __shfl_xor(vsum, 2);
    vsum += __shfl_xor(vsum, 4);
    vsum += __shfl_xor(vsum, 8);
    rs[r] = 1.f / vsum;
  }

  // ---------------- Pass B: attn write + PV ----------------
  f32x4 oacc[4];
  #pragma unroll
  for (int dt = 0; dt < 4; ++dt) oacc[dt] = (f32x4){0.f, 0.f, 0.f, 0.f};

  float* __restrict__ arow[4];
  #pragma unroll
  for (int r = 0; r < 4; ++r)
    arow[r] = attn_out + ((size_t)bh * S_ + q0 + rloc[r]) * S_;

  // prologue: stage K tile 0 + V tile 0 (safe: pass A ended on a barrier)
  #pragma unroll
  for (int rep = 0; rep < 2; ++rep) {
    kreg[rep] = *(const int4*)&khb[(size_t)(rep * 32 + srow) * 64 + scol];
    vreg[rep] = *(const int4*)&vtb[(size_t)(rep * 32 + srow) * S_ + scol];
  }
  #pragma unroll
  for (int rep = 0; rep < 2; ++rep) {
    *(int4*)&Ks[(rep * 32 + srow) * 72 + scol] = kreg[rep];
    *(int4*)&Vs[(rep * 32 + srow) * 72 + scol] = vreg[rep];
  }
  __syncthreads();

  for (int kt0 = 0; kt0 < S_; kt0 += 64) {
    const bool has_next = (kt0 + 64 < S_);
    if (has_next) {
      #pragma unroll
      for (int rep = 0; rep < 2; ++rep) {
        kreg[rep] = *(const int4*)&khb[(size_t)(kt0 + 64 + rep * 32 + srow) * 64 + scol];
        vreg[rep] = *(const int4*)&vtb[(size_t)(rep * 32 + srow) * S_ + kt0 + 64 + scol];
      }
    }
    #pragma unroll
    for (int nt = 0; nt < 4; ++nt) {
      bf16x8 kf0 = *(bf16x8*)&Ks[(nt * 16 + l15) * 72 + quad * 8];
      bf16x8 kf1 = *(bf16x8*)&Ks[(nt * 16 + l15) * 72 + 32 + quad * 8];
      f32x4 c = (f32x4){0.f, 0.f, 0.f, 0.f};
      c = MFMA16(qf0, kf0, c);
      c = MFMA16(qf1, kf1, c);
      int kj = kt0 + nt * 16 + l15;
      int mk = smAll[kj];
      #pragma unroll
      for (int r = 0; r < 4; ++r) {
        float ss = c[r] * 0.125f;
        bool keep = (mqr[r] & mk) || (qir[r] == kj);
        ss = keep ? ss : NEG_FILL;
        float p = __expf(ss) * rs[r];
        arow[r][kj] = p;
        Ps[rloc[r] * 72 + nt * 16 + l15] = f2b(p);
      }
    }
    // wave-local P transpose readback: same wave wrote these rows -> no barrier
    bf16x8 pf0 = *(bf16x8*)&Ps[(wave * 16 + l15) * 72 + quad * 8];
    bf16x8 pf1 = *(bf16x8*)&Ps[(wave * 16 + l15) * 72 + 32 + quad * 8];
    #pragma unroll
    for (int dt = 0; dt < 4; ++dt) {
      bf16x8 vf0 = *(bf16x8*)&Vs[(dt * 16 + l15) * 72 + quad * 8];
      bf16x8 vf1 = *(bf16x8*)&Vs[(dt * 16 + l15) * 72 + 32 + quad * 8];
      oacc[dt] = MFMA16(pf0, vf0, oacc[dt]);
      oacc[dt] = MFMA16(pf1, vf1, oacc[dt]);
    }
    __syncthreads();
    if (has_next) {
      #pragma unroll
      for (int rep = 0; rep < 2; ++rep) {
        *(int4*)&Ks[(rep * 32 + srow) * 72 + scol] = kreg[rep];
        *(int4*)&Vs[(rep * 32 + srow) * 72 + scol] = vreg[rep];
      }
    }
    __syncthreads();
  }

  // ---- write O tile (bf16) ----
  #pragma unroll
  for (int dt = 0; dt < 4; ++dt) {
    int d = h * 64 + dt * 16 + l15;
    #pragma unroll
    for (int r = 0; r < 4; ++r)
      ohb[((size_t)b * S_ + q0 + rloc[r]) * 512 + d] = f2b(oacc[dt][r]);
  }
}

// ---------------------------------------------------------------------------
// out = ohb @ Wo + residual(q), MFMA bf16, fp32 out. Async-split staging.
// ---------------------------------------------------------------------------
__global__ __launch_bounds__(256) void out_mfma(
    const short* __restrict__ ohb, const short* __restrict__ Wot,
    const float* __restrict__ resid, float* __restrict__ out)
{
  __shared__ short Xs[64 * 72];
  __shared__ short Wsh[64 * 72];

  const int t = threadIdx.x;
  const int wave = t >> 6, lane = t & 63, quad = lane >> 4, l15 = lane & 15;
  const int tile_n = blockIdx.x * 64;
  const int tile_m = blockIdx.y * 64;
  const int srow = t >> 3, sc = (t & 7) * 8;

  f32x4 acc[4];
  #pragma unroll
  for (int nt = 0; nt < 4; ++nt) acc[nt] = (f32x4){0.f, 0.f, 0.f, 0.f};

  int4 xreg[2], wreg[2];
  #pragma unroll
  for (int rep = 0; rep < 2; ++rep) {
    xreg[rep] = *(const int4*)&ohb[(size_t)(tile_m + rep * 32 + srow) * 512 + sc];
    wreg[rep] = *(const int4*)&Wot[(size_t)(tile_n + rep * 32 + srow) * 512 + sc];
  }
  #pragma unroll
  for (int rep = 0; rep < 2; ++rep) {
    *(int4*)&Xs[(rep * 32 + srow) * 72 + sc] = xreg[rep];
    *(int4*)&Wsh[(rep * 32 + srow) * 72 + sc] = wreg[rep];
  }
  __syncthreads();

  for (int k0 = 0; k0 < 512; k0 += 64) {
    const bool has_next = (k0 + 64 < 512);
    if (has_next) {
      #pragma unroll
      for (int rep = 0; rep < 2; ++rep) {
        xreg[rep] = *(const int4*)&ohb[(size_t)(tile_m + rep * 32 + srow) * 512 + k0 + 64 + sc];
        wreg[rep] = *(const int4*)&Wot[(size_t)(tile_n + rep * 32 + srow) * 512 + k0 + 64 + sc];
      }
    }
    #pragma unroll
    for (int ks = 0; ks < 2; ++ks) {
      bf16x8 af = *(bf16x8*)&Xs[(wave * 16 + l15) * 72 + ks * 32 + quad * 8];
      #pragma unroll
      for (int nt = 0; nt < 4; ++nt) {
        bf16x8 bfr = *(bf16x8*)&Wsh[(nt * 16 + l15) * 72 + ks * 32 + quad * 8];
        acc[nt] = MFMA16(af, bfr, acc[nt]);
      }
    }
    __syncthreads();
    if (has_next) {
      #pragma unroll
      for (int rep = 0; rep < 2; ++rep) {
        *(int4*)&Xs[(rep * 32 + srow) * 72 + sc] = xreg[rep];
        *(int4*)&Wsh[(rep * 32 + srow) * 72 + sc] = wreg[rep];
      }
    }
    __syncthreads();
  }

  #pragma unroll
  for (int nt = 0; nt < 4; ++nt) {
    int c = tile_n + nt * 16 + l15;
    #pragma unroll
    for (int r = 0; r < 4; ++r) {
      size_t row = tile_m + wave * 16 + quad * 4 + r;
      out[row * 512 + c] = acc[nt][r] + resid[row * 512 + c];
    }
  }
}

// ---------------------------------------------------------------------------
// LayerNorm over last dim (512), one wave per row, in place.
// ---------------------------------------------------------------------------
__global__ __launch_bounds__(256) void ln_kernel(
    float* __restrict__ io, const float* __restrict__ gamma, const float* __restrict__ beta)
{
  const int wid  = threadIdx.x >> 6;
  const int lane = threadIdx.x & 63;
  const size_t row = (size_t)blockIdx.x * 4 + wid;
  const size_t base = row * 512 + lane * 8;

  float4 x0 = *(const float4*)&io[base];
  float4 x1 = *(const float4*)&io[base + 4];
  float xs[8] = {x0.x, x0.y, x0.z, x0.w, x1.x, x1.y, x1.z, x1.w};

  float s = 0.f, s2 = 0.f;
  #pragma unroll
  for (int i = 0; i < 8; ++i) { s += xs[i]; s2 = fmaf(xs[i], xs[i], s2); }
  #pragma unroll
  for (int m = 1; m < 64; m <<= 1) {
    s  += __shfl_xor(s, m);
    s2 += __shfl_xor(s2, m);
  }
  float mu  = s * (1.f / 512.f);
  float var = s2 * (1.f / 512.f) - mu * mu;
  float rsq = rsqrtf(var + 1e-6f);

  float4 g0 = *(const float4*)&gamma[lane * 8];
  float4 g1 = *(const float4*)&gamma[lane * 8 + 4];
  float4 b0 = *(const float4*)&beta[lane * 8];
  float4 b1 = *(const float4*)&beta[lane * 8 + 4];
  float gs[8] = {g0.x, g0.y, g0.z, g0.w, g1.x, g1.y, g1.z, g1.w};
  float bs[8] = {b0.x, b0.y, b0.z, b0.w, b1.x, b1.y, b1.z, b1.w};

  float ys[8];
  #pragma unroll
  for (int i = 0; i < 8; ++i) ys[i] = (xs[i] - mu) * rsq * gs[i] + bs[i];
  *(float4*)&io[base]     = make_float4(ys[0], ys[1], ys[2], ys[3]);
  *(float4*)&io[base + 4] = make_float4(ys[4], ys[5], ys[6], ys[7]);
}

// ---------------------------------------------------------------------------
extern "C" void kernel_launch(void* const* d_in, const int* in_sizes, int n_in,
                              void* d_out, int out_size, void* d_ws, size_t ws_size,
                              hipStream_t stream)
{
  const float* q     = (const float*)d_in[0];
  const float* k     = (const float*)d_in[1];
  const float* v     = (const float*)d_in[2];
  const int*  smask  = (const int*)d_in[3];
  const float* Wq    = (const float*)d_in[4];
  const float* Wk    = (const float*)d_in[5];
  const float* Wv    = (const float*)d_in[6];
  const float* Wo    = (const float*)d_in[7];
  const float* gamma = (const float*)d_in[8];
  const float* beta  = (const float*)d_in[9];

  float* out  = (float*)d_out;
  float* attn = out + (size_t)B_ * S_ * D_;

  short* wsS = (short*)d_ws;
  short* qh  = wsS;                    // [32 bh][2048][64]
  short* kh  = qh + 4194304;
  short* vt  = kh + 4194304;           // [32 bh][64][2048]
  short* ohb = vt + 4194304;           // [8192][512]
  short* Wqt = ohb + 4194304;          // [512][512] each
  short* Wkt = Wqt + 262144;
  short* Wvt = Wkt + 262144;
  short* Wot = Wvt + 262144;

  prep_wt<<<dim3(8, 8, 4), 256, 0, stream>>>(Wq, Wk, Wv, Wo, Wqt, Wkt, Wvt, Wot);
  qkv_mfma<<<dim3(8, 128, 3), 256, 0, stream>>>(q, k, v, Wqt, Wkt, Wvt, qh, kh, vt);
  attn_mfma<<<dim3(32, 32), 256, 0, stream>>>(qh, kh, vt, smask, attn, ohb);
  out_mfma<<<dim3(8, 128), 256, 0, stream>>>(ohb, Wot, q, out);
  ln_kernel<<<2048, 256, 0, stream>>>(out, gamma, beta);
}

// Round 3
// 724.506 us; speedup vs baseline: 1.3471x; 1.3072x over previous
//
#include <hip/hip_runtime.h>
#include <math.h>

#define B_ 4
#define S_ 2048
#define D_ 512
#define H_ 8
#define NEG_FILL (-1e-9f)

typedef __attribute__((ext_vector_type(8))) short bf16x8;
typedef __attribute__((ext_vector_type(4))) float f32x4;

#define MFMA16(A, Bm, C) __builtin_amdgcn_mfma_f32_16x16x32_bf16((A), (Bm), (C), 0, 0, 0)

__device__ __forceinline__ short f2b(float f) {
  union { float f; unsigned u; } x;
  x.f = f;
  unsigned r = x.u + 0x7fffu + ((x.u >> 16) & 1u);
  return (short)(r >> 16);
}

// ---------------------------------------------------------------------------
// prep: W[512x512] fp32 (k-major) -> Wt[n][k] bf16 (transposed), z picks matrix
// ---------------------------------------------------------------------------
__global__ __launch_bounds__(256) void prep_wt(
    const float* __restrict__ Wq, const float* __restrict__ Wk,
    const float* __restrict__ Wv, const float* __restrict__ Wo,
    short* __restrict__ Wqt, short* __restrict__ Wkt,
    short* __restrict__ Wvt, short* __restrict__ Wot)
{
  const float* W; short* Wt;
  switch (blockIdx.z) {
    case 0: W = Wq; Wt = Wqt; break;
    case 1: W = Wk; Wt = Wkt; break;
    case 2: W = Wv; Wt = Wvt; break;
    default: W = Wo; Wt = Wot; break;
  }
  __shared__ float Ws[64 * 68];
  const int t = threadIdx.x;
  const int n0 = blockIdx.x * 64, k0 = blockIdx.y * 64;

  #pragma unroll
  for (int rep = 0; rep < 4; ++rep) {
    int e4 = rep * 256 + t;           // float4 units
    int r = e4 >> 4, c0 = (e4 & 15) * 4;
    *(float4*)&Ws[r * 68 + c0] = *(const float4*)&W[(size_t)(k0 + r) * 512 + n0 + c0];
  }
  __syncthreads();

  int rn = t >> 2;                    // out row (n)
  int kb = (t & 3) * 16;              // out col base (k)
  union { short s[8]; int4 v; } pk;
  #pragma unroll
  for (int half = 0; half < 2; ++half) {
    #pragma unroll
    for (int i = 0; i < 8; ++i)
      pk.s[i] = f2b(Ws[(kb + half * 8 + i) * 68 + rn]);
    *(int4*)&Wt[(size_t)(n0 + rn) * 512 + k0 + kb + half * 8] = pk.v;
  }
}

// ---------------------------------------------------------------------------
// QKV projection, MFMA bf16 (round-0 proven structure).
// z=0 -> qh[bh][s][64], z=1 -> kh[bh][s][64], z=2 -> vt[bh][d][2048]
// ---------------------------------------------------------------------------
__global__ __launch_bounds__(256) void qkv_mfma(
    const float* __restrict__ q, const float* __restrict__ k, const float* __restrict__ v,
    const short* __restrict__ Wqt, const short* __restrict__ Wkt, const short* __restrict__ Wvt,
    short* __restrict__ qh, short* __restrict__ kh, short* __restrict__ vt)
{
  const int z = blockIdx.z;
  const float* X = (z == 0) ? q : (z == 1) ? k : v;
  const short* Wt = (z == 0) ? Wqt : (z == 1) ? Wkt : Wvt;

  __shared__ short Xs[64 * 72];
  __shared__ short Wsh[64 * 72];

  const int t = threadIdx.x;
  const int wave = t >> 6, lane = t & 63, quad = lane >> 4, l15 = lane & 15;
  const int tile_n = blockIdx.x * 64;
  const int tile_m = blockIdx.y * 64;

  f32x4 acc[4];
  #pragma unroll
  for (int nt = 0; nt < 4; ++nt) acc[nt] = (f32x4){0.f, 0.f, 0.f, 0.f};

  for (int k0 = 0; k0 < 512; k0 += 64) {
    __syncthreads();
    #pragma unroll
    for (int rep = 0; rep < 4; ++rep) {
      int e4 = rep * 256 + t;
      int row = e4 >> 4, c0 = (e4 & 15) * 4;
      float4 xv = *(const float4*)&X[(size_t)(tile_m + row) * 512 + k0 + c0];
      *(short4*)&Xs[row * 72 + c0] =
          make_short4(f2b(xv.x), f2b(xv.y), f2b(xv.z), f2b(xv.w));
    }
    #pragma unroll
    for (int rep = 0; rep < 2; ++rep) {
      int e = rep * 256 + t;
      int row = e >> 3, c0 = (e & 7) * 8;
      *(int4*)&Wsh[row * 72 + c0] = *(const int4*)&Wt[(size_t)(tile_n + row) * 512 + k0 + c0];
    }
    __syncthreads();
    #pragma unroll
    for (int ks = 0; ks < 2; ++ks) {
      bf16x8 af = *(bf16x8*)&Xs[(wave * 16 + l15) * 72 + ks * 32 + quad * 8];
      #pragma unroll
      for (int nt = 0; nt < 4; ++nt) {
        bf16x8 bfr = *(bf16x8*)&Wsh[(nt * 16 + l15) * 72 + ks * 32 + quad * 8];
        acc[nt] = MFMA16(af, bfr, acc[nt]);
      }
    }
  }

  const int h = tile_n >> 6;
  if (z < 2) {
    short* Y = (z == 0) ? qh : kh;
    #pragma unroll
    for (int nt = 0; nt < 4; ++nt) {
      int d = nt * 16 + l15;
      #pragma unroll
      for (int r = 0; r < 4; ++r) {
        int row = tile_m + wave * 16 + quad * 4 + r;
        int b = row >> 11, s = row & (S_ - 1);
        Y[(((size_t)(b * H_ + h)) * S_ + s) * 64 + d] = f2b(acc[nt][r]);
      }
    }
  } else {
    int row0 = tile_m + wave * 16 + quad * 4;
    int b = row0 >> 11, s0 = row0 & (S_ - 1);
    #pragma unroll
    for (int nt = 0; nt < 4; ++nt) {
      int d = nt * 16 + l15;
      short4 pk = make_short4(f2b(acc[nt][0]), f2b(acc[nt][1]),
                              f2b(acc[nt][2]), f2b(acc[nt][3]));
      *(short4*)&vt[(((size_t)(b * H_ + h)) * 64 + d) * S_ + s0] = pk;
    }
  }
}

// ---------------------------------------------------------------------------
// Fused attention, MFMA bf16. Double-buffered K/V in LDS -> ONE barrier per
// K-tile; reg-staged prefetch (loads at loop top, ds_write before barrier);
// XOR-swizzled linear 128B-row tiles (conflict-free, involution on write+read);
// non-temporal attn stores (537 MB never re-read -> keep L2 for K/V).
// Mask row cached whole in LDS; Q fragments direct from global; P tile
// wave-local (lgkmcnt only). XCD-bijective block swizzle.
// ---------------------------------------------------------------------------
__global__ __launch_bounds__(256) void attn_mfma(
    const short* __restrict__ qh, const short* __restrict__ kh,
    const short* __restrict__ vt, const int* __restrict__ src_mask,
    float* __restrict__ attn_out, short* __restrict__ ohb)
{
  const int t = threadIdx.x;
  const int wave = t >> 6, lane = t & 63, quad = lane >> 4, l15 = lane & 15;

  // 1024 blocks, 8 XCDs -> contiguous chunk of 128 nl per XCD.
  const int lin = blockIdx.y * 32 + blockIdx.x;
  const int nl  = (lin & 7) * 128 + (lin >> 3);
  const int bh = nl >> 5, b = bh >> 3, h = bh & 7;
  const int q0 = (nl & 31) * 64;

  __shared__ __align__(16) short KV[4][64 * 64];  // [0..1] K dbuf, [2..3] V dbuf
  __shared__ __align__(16) short Ps[4][16 * 72];  // per-wave P tile
  __shared__ __align__(16) int smAll[S_];         // full mask row for this b

  const short* __restrict__ khb = kh + (size_t)bh * S_ * 64;
  const short* __restrict__ vtb = vt + (size_t)bh * 64 * S_;

  // staging geometry: thread t -> rows sr, sr+32; 16B slot sc within 128B row
  const int sr = t >> 3, sc = t & 7;
  const int wofs0 = sr * 128 + ((sc ^ (sr & 7)) << 4);          // swizzled write
  const int wofs1 = (sr + 32) * 128 + ((sc ^ (sr & 7)) << 4);
  // read swizzle per lane: slot (ks*4+quad) ^ (row&7), row&7 == l15&7
  const int rofs0 = ((quad ^ (l15 & 7)) << 4);
  const int rofs1 = (((4 + quad) ^ (l15 & 7)) << 4);

  // Q fragments straight from global (row = wave*16+l15).
  const size_t qrow = (size_t)bh * S_ + q0 + wave * 16 + l15;
  const bf16x8 qf0 = *(const bf16x8*)&qh[qrow * 64 + quad * 8];
  const bf16x8 qf1 = *(const bf16x8*)&qh[qrow * 64 + 32 + quad * 8];

  // ---- prologue: mask row + K tile 0 ----
  int4 kreg0, kreg1, vreg0, vreg1;
  int4 mreg0 = *(const int4*)&src_mask[b * S_ + t * 4];
  int4 mreg1 = *(const int4*)&src_mask[b * S_ + (256 + t) * 4];
  kreg0 = *(const int4*)&khb[(size_t)sr * 64 + sc * 8];
  kreg1 = *(const int4*)&khb[(size_t)(sr + 32) * 64 + sc * 8];
  *(int4*)&smAll[t * 4] = mreg0;
  *(int4*)&smAll[(256 + t) * 4] = mreg1;
  *(int4*)((char*)KV[0] + wofs0) = kreg0;
  *(int4*)((char*)KV[0] + wofs1) = kreg1;
  __syncthreads();

  int rloc[4], mqr[4], qir[4];
  #pragma unroll
  for (int r = 0; r < 4; ++r) {
    rloc[r] = wave * 16 + quad * 4 + r;
    qir[r] = q0 + rloc[r];
    mqr[r] = smAll[qir[r]];
  }

  // ---------------- Pass A: exp-sums ----------------
  float rs[4] = {0.f, 0.f, 0.f, 0.f};
  for (int step = 0; step < 32; ++step) {
    const int kt0 = step * 64;
    const int cur = step & 1;
    if (step < 31) {
      kreg0 = *(const int4*)&khb[(size_t)(kt0 + 64 + sr) * 64 + sc * 8];
      kreg1 = *(const int4*)&khb[(size_t)(kt0 + 64 + sr + 32) * 64 + sc * 8];
    }
    const char* Kc = (const char*)KV[cur];
    #pragma unroll
    for (int nt = 0; nt < 4; ++nt) {
      bf16x8 kf0 = *(const bf16x8*)(Kc + (nt * 16 + l15) * 128 + rofs0);
      bf16x8 kf1 = *(const bf16x8*)(Kc + (nt * 16 + l15) * 128 + rofs1);
      f32x4 c = (f32x4){0.f, 0.f, 0.f, 0.f};
      c = MFMA16(qf0, kf0, c);
      c = MFMA16(qf1, kf1, c);
      int kj = kt0 + nt * 16 + l15;
      int mk = smAll[kj];
      #pragma unroll
      for (int r = 0; r < 4; ++r) {
        float ss = c[r] * 0.125f;
        bool keep = (mqr[r] & mk) || (qir[r] == kj);
        ss = keep ? ss : NEG_FILL;
        rs[r] += __expf(ss);
      }
    }
    if (step < 31) {
      *(int4*)((char*)KV[cur ^ 1] + wofs0) = kreg0;
      *(int4*)((char*)KV[cur ^ 1] + wofs1) = kreg1;
    }
    __syncthreads();
  }
  // reduce across the 16 lanes holding one row's columns; keep inverse
  #pragma unroll
  for (int r = 0; r < 4; ++r) {
    float vsum = rs[r];
    vsum += __shfl_xor(vsum, 1);
    vsum += __shfl_xor(vsum, 2);
    vsum += __shfl_xor(vsum, 4);
    vsum += __shfl_xor(vsum, 8);
    rs[r] = 1.f / vsum;
  }

  // ---------------- Pass B: attn write + PV ----------------
  f32x4 oacc[4];
  #pragma unroll
  for (int dt = 0; dt < 4; ++dt) oacc[dt] = (f32x4){0.f, 0.f, 0.f, 0.f};

  float* __restrict__ arow[4];
  #pragma unroll
  for (int r = 0; r < 4; ++r)
    arow[r] = attn_out + ((size_t)bh * S_ + q0 + rloc[r]) * S_;

  short* __restrict__ ps = Ps[wave];

  // prologue: K tile 0 -> KV[0], V tile 0 -> KV[2]  (pass A ended on barrier)
  kreg0 = *(const int4*)&khb[(size_t)sr * 64 + sc * 8];
  kreg1 = *(const int4*)&khb[(size_t)(sr + 32) * 64 + sc * 8];
  vreg0 = *(const int4*)&vtb[(size_t)sr * S_ + sc * 8];
  vreg1 = *(const int4*)&vtb[(size_t)(sr + 32) * S_ + sc * 8];
  *(int4*)((char*)KV[0] + wofs0) = kreg0;
  *(int4*)((char*)KV[0] + wofs1) = kreg1;
  *(int4*)((char*)KV[2] + wofs0) = vreg0;
  *(int4*)((char*)KV[2] + wofs1) = vreg1;
  __syncthreads();

  for (int step = 0; step < 32; ++step) {
    const int kt0 = step * 64;
    const int cur = step & 1;
    if (step < 31) {
      kreg0 = *(const int4*)&khb[(size_t)(kt0 + 64 + sr) * 64 + sc * 8];
      kreg1 = *(const int4*)&khb[(size_t)(kt0 + 64 + sr + 32) * 64 + sc * 8];
      vreg0 = *(const int4*)&vtb[(size_t)sr * S_ + kt0 + 64 + sc * 8];
      vreg1 = *(const int4*)&vtb[(size_t)(sr + 32) * S_ + kt0 + 64 + sc * 8];
    }
    const char* Kc = (const char*)KV[cur];
    const char* Vc = (const char*)KV[2 + cur];
    #pragma unroll
    for (int nt = 0; nt < 4; ++nt) {
      bf16x8 kf0 = *(const bf16x8*)(Kc + (nt * 16 + l15) * 128 + rofs0);
      bf16x8 kf1 = *(const bf16x8*)(Kc + (nt * 16 + l15) * 128 + rofs1);
      f32x4 c = (f32x4){0.f, 0.f, 0.f, 0.f};
      c = MFMA16(qf0, kf0, c);
      c = MFMA16(qf1, kf1, c);
      int kj = kt0 + nt * 16 + l15;
      int mk = smAll[kj];
      #pragma unroll
      for (int r = 0; r < 4; ++r) {
        float ss = c[r] * 0.125f;
        bool keep = (mqr[r] & mk) || (qir[r] == kj);
        ss = keep ? ss : NEG_FILL;
        float p = __expf(ss) * rs[r];
        __builtin_nontemporal_store(p, &arow[r][kj]);
        ps[(quad * 4 + r) * 72 + nt * 16 + l15] = f2b(p);
      }
    }
    // wave-local P transpose readback (same wave wrote these rows)
    bf16x8 pf0 = *(bf16x8*)&ps[l15 * 72 + quad * 8];
    bf16x8 pf1 = *(bf16x8*)&ps[l15 * 72 + 32 + quad * 8];
    #pragma unroll
    for (int dt = 0; dt < 4; ++dt) {
      bf16x8 vf0 = *(const bf16x8*)(Vc + (dt * 16 + l15) * 128 + rofs0);
      bf16x8 vf1 = *(const bf16x8*)(Vc + (dt * 16 + l15) * 128 + rofs1);
      oacc[dt] = MFMA16(pf0, vf0, oacc[dt]);
      oacc[dt] = MFMA16(pf1, vf1, oacc[dt]);
    }
    if (step < 31) {
      *(int4*)((char*)KV[cur ^ 1] + wofs0) = kreg0;
      *(int4*)((char*)KV[cur ^ 1] + wofs1) = kreg1;
      *(int4*)((char*)KV[2 + (cur ^ 1)] + wofs0) = vreg0;
      *(int4*)((char*)KV[2 + (cur ^ 1)] + wofs1) = vreg1;
    }
    __syncthreads();
  }

  // ---- write O tile (bf16) ----
  #pragma unroll
  for (int dt = 0; dt < 4; ++dt) {
    int d = h * 64 + dt * 16 + l15;
    #pragma unroll
    for (int r = 0; r < 4; ++r)
      ohb[((size_t)b * S_ + q0 + rloc[r]) * 512 + d] = f2b(oacc[dt][r]);
  }
}

// ---------------------------------------------------------------------------
// out = ohb @ Wo + residual(q), MFMA bf16, fp32 out (round-0 proven structure).
// ---------------------------------------------------------------------------
__global__ __launch_bounds__(256) void out_mfma(
    const short* __restrict__ ohb, const short* __restrict__ Wot,
    const float* __restrict__ resid, float* __restrict__ out)
{
  __shared__ short Xs[64 * 72];
  __shared__ short Wsh[64 * 72];

  const int t = threadIdx.x;
  const int wave = t >> 6, lane = t & 63, quad = lane >> 4, l15 = lane & 15;
  const int tile_n = blockIdx.x * 64;
  const int tile_m = blockIdx.y * 64;

  f32x4 acc[4];
  #pragma unroll
  for (int nt = 0; nt < 4; ++nt) acc[nt] = (f32x4){0.f, 0.f, 0.f, 0.f};

  for (int k0 = 0; k0 < 512; k0 += 64) {
    __syncthreads();
    #pragma unroll
    for (int rep = 0; rep < 2; ++rep) {
      int e = rep * 256 + t;
      int row = e >> 3, c0 = (e & 7) * 8;
      *(int4*)&Xs[row * 72 + c0] = *(const int4*)&ohb[(size_t)(tile_m + row) * 512 + k0 + c0];
      *(int4*)&Wsh[row * 72 + c0] = *(const int4*)&Wot[(size_t)(tile_n + row) * 512 + k0 + c0];
    }
    __syncthreads();
    #pragma unroll
    for (int ks = 0; ks < 2; ++ks) {
      bf16x8 af = *(bf16x8*)&Xs[(wave * 16 + l15) * 72 + ks * 32 + quad * 8];
      #pragma unroll
      for (int nt = 0; nt < 4; ++nt) {
        bf16x8 bfr = *(bf16x8*)&Wsh[(nt * 16 + l15) * 72 + ks * 32 + quad * 8];
        acc[nt] = MFMA16(af, bfr, acc[nt]);
      }
    }
  }

  #pragma unroll
  for (int nt = 0; nt < 4; ++nt) {
    int c = tile_n + nt * 16 + l15;
    #pragma unroll
    for (int r = 0; r < 4; ++r) {
      size_t row = tile_m + wave * 16 + quad * 4 + r;
      out[row * 512 + c] = acc[nt][r] + resid[row * 512 + c];
    }
  }
}

// ---------------------------------------------------------------------------
// LayerNorm over last dim (512), one wave per row, in place.
// ---------------------------------------------------------------------------
__global__ __launch_bounds__(256) void ln_kernel(
    float* __restrict__ io, const float* __restrict__ gamma, const float* __restrict__ beta)
{
  const int wid  = threadIdx.x >> 6;
  const int lane = threadIdx.x & 63;
  const size_t row = (size_t)blockIdx.x * 4 + wid;
  const size_t base = row * 512 + lane * 8;

  float4 x0 = *(const float4*)&io[base];
  float4 x1 = *(const float4*)&io[base + 4];
  float xs[8] = {x0.x, x0.y, x0.z, x0.w, x1.x, x1.y, x1.z, x1.w};

  float s = 0.f, s2 = 0.f;
  #pragma unroll
  for (int i = 0; i < 8; ++i) { s += xs[i]; s2 = fmaf(xs[i], xs[i], s2); }
  #pragma unroll
  for (int m = 1; m < 64; m <<= 1) {
    s  += __shfl_xor(s, m);
    s2 += __shfl_xor(s2, m);
  }
  float mu  = s * (1.f / 512.f);
  float var = s2 * (1.f / 512.f) - mu * mu;
  float rsq = rsqrtf(var + 1e-6f);

  float4 g0 = *(const float4*)&gamma[lane * 8];
  float4 g1 = *(const float4*)&gamma[lane * 8 + 4];
  float4 b0 = *(const float4*)&beta[lane * 8];
  float4 b1 = *(const float4*)&beta[lane * 8 + 4];
  float gs[8] = {g0.x, g0.y, g0.z, g0.w, g1.x, g1.y, g1.z, g1.w};
  float bs[8] = {b0.x, b0.y, b0.z, b0.w, b1.x, b1.y, b1.z, b1.w};

  float ys[8];
  #pragma unroll
  for (int i = 0; i < 8; ++i) ys[i] = (xs[i] - mu) * rsq * gs[i] + bs[i];
  *(float4*)&io[base]     = make_float4(ys[0], ys[1], ys[2], ys[3]);
  *(float4*)&io[base + 4] = make_float4(ys[4], ys[5], ys[6], ys[7]);
}

// ---------------------------------------------------------------------------
extern "C" void kernel_launch(void* const* d_in, const int* in_sizes, int n_in,
                              void* d_out, int out_size, void* d_ws, size_t ws_size,
                              hipStream_t stream)
{
  const float* q     = (const float*)d_in[0];
  const float* k     = (const float*)d_in[1];
  const float* v     = (const float*)d_in[2];
  const int*  smask  = (const int*)d_in[3];
  const float* Wq    = (const float*)d_in[4];
  const float* Wk    = (const float*)d_in[5];
  const float* Wv    = (const float*)d_in[6];
  const float* Wo    = (const float*)d_in[7];
  const float* gamma = (const float*)d_in[8];
  const float* beta  = (const float*)d_in[9];

  float* out  = (float*)d_out;
  float* attn = out + (size_t)B_ * S_ * D_;

  short* wsS = (short*)d_ws;
  short* qh  = wsS;                    // [32 bh][2048][64]
  short* kh  = qh + 4194304;
  short* vt  = kh + 4194304;           // [32 bh][64][2048]
  short* ohb = vt + 4194304;           // [8192][512]
  short* Wqt = ohb + 4194304;          // [512][512] each
  short* Wkt = Wqt + 262144;
  short* Wvt = Wkt + 262144;
  short* Wot = Wvt + 262144;

  prep_wt<<<dim3(8, 8, 4), 256, 0, stream>>>(Wq, Wk, Wv, Wo, Wqt, Wkt, Wvt, Wot);
  qkv_mfma<<<dim3(8, 128, 3), 256, 0, stream>>>(q, k, v, Wqt, Wkt, Wvt, qh, kh, vt);
  attn_mfma<<<dim3(32, 32), 256, 0, stream>>>(qh, kh, vt, smask, attn, ohb);
  out_mfma<<<dim3(8, 128), 256, 0, stream>>>(ohb, Wot, q, out);
  ln_kernel<<<2048, 256, 0, stream>>>(out, gamma, beta);
}